// Round 2
// baseline (1150.096 us; speedup 1.0000x reference)
//
#include <hip/hip_runtime.h>

#define DI __device__ __forceinline__

typedef short bfrag8 __attribute__((ext_vector_type(8)));
typedef float ffrag4 __attribute__((ext_vector_type(4)));

DI ushort f2b(float f){
  union { float f; unsigned u; } v; v.f = f;
  unsigned u = v.u;
  u += 0x7FFF + ((u >> 16) & 1);   // round-to-nearest-even
  return (ushort)(u >> 16);
}
DI float b2f(ushort h){
  union { unsigned u; float f; } v; v.u = ((unsigned)h) << 16;
  return v.f;
}
DI float sigm(float x){ return 1.0f / (1.0f + __expf(-x)); }
DI float tanh_(float x){ return 1.0f - 2.0f / (1.0f + __expf(2.0f * x)); }
DI float elu_(float x){ return x > 0.f ? x : __expf(x) - 1.f; }

// ---------------------------------------------------------------------------
// Tiny kernel: attention probs for a pair of GAT layers from sample 0.
// 1 block x 576 threads.
// ---------------------------------------------------------------------------
__global__ void k_probs(const float* xf, const ushort* xb, int in_c,
                        const float* W1, const float* b1, const float* a1, int hc1, int c1,
                        const float* W2, const float* b2, const float* a2, int hc2, int c2,
                        float* outA, float* outB)
{
  __shared__ float xs[12 * 22];
  __shared__ float h1[12 * 16];
  __shared__ float lg[4 * 144];
  __shared__ float pr[4 * 144];
  __shared__ float h1e[12 * 16];
  __shared__ float h2[12 * 24];
  const int t = threadIdx.x;
  const unsigned adj[12] = {0xC21u,0x482u,0x844u,0x048u,0x030u,0x031u,
                            0x44Cu,0x282u,0xF00u,0x780u,0xF43u,0xD05u};
  if (t < 12 * in_c){
    if (xf) xs[t] = xf[t];
    else    xs[t] = b2f(xb[t]);
  }
  __syncthreads();
  if (t < 12 * hc1){
    int i = t / hc1, o = t % hc1;
    float v = b1[o];
    for (int k = 0; k < in_c; k++) v += xs[i * in_c + k] * W1[k * hc1 + o];
    h1[t] = v;
  }
  __syncthreads();
  {
    int h = t / 144, ij = t % 144, i = ij / 12, j = ij % 12;
    float v;
    if ((adj[i] >> j) & 1){
      v = 0.f;
      for (int c = 0; c < c1; c++)
        v += a1[h*2*c1 + c] * h1[i*hc1 + h*c1 + c] + a1[h*2*c1 + c1 + c] * h1[j*hc1 + h*c1 + c];
      v = v > 0.f ? v : 0.2f * v;
    } else v = -9e15f;
    lg[t] = v;
  }
  __syncthreads();
  if (t < 48){
    int h = t / 12, i = t % 12;
    const float* row = &lg[h*144 + i*12];
    float m = row[0];
    for (int j = 1; j < 12; j++) m = fmaxf(m, row[j]);
    float e[12], s = 0.f;
    for (int j = 0; j < 12; j++){ e[j] = __expf(row[j] - m); s += e[j]; }
    float inv = 1.f / s;
    for (int j = 0; j < 12; j++){
      float p = e[j] * inv;
      pr[h*144 + i*12 + j] = p;
      outA[h*144 + i*12 + j] = p;
    }
  }
  __syncthreads();
  if (t < 12 * hc1){
    int i = t / hc1, o = t % hc1, h = o / c1;
    float v = 0.f;
    for (int j = 0; j < 12; j++) v += pr[h*144 + i*12 + j] * h1[j*hc1 + o];
    h1e[t] = elu_(v);
  }
  __syncthreads();
  if (t < 12 * hc2){
    int i = t / hc2, o = t % hc2;
    float v = b2[o];
    for (int k = 0; k < hc1; k++) v += h1e[i*hc1 + k] * W2[k*hc2 + o];
    h2[t] = v;
  }
  __syncthreads();
  {
    int h = t / 144, ij = t % 144, i = ij / 12, j = ij % 12;
    float v;
    if ((adj[i] >> j) & 1){
      v = 0.f;
      for (int c = 0; c < c2; c++)
        v += a2[h*2*c2 + c] * h2[i*hc2 + h*c2 + c] + a2[h*2*c2 + c2 + c] * h2[j*hc2 + h*c2 + c];
      v = v > 0.f ? v : 0.2f * v;
    } else v = -9e15f;
    lg[t] = v;
  }
  __syncthreads();
  if (t < 48){
    int h = t / 12, i = t % 12;
    const float* row = &lg[h*144 + i*12];
    float m = row[0];
    for (int j = 1; j < 12; j++) m = fmaxf(m, row[j]);
    float e[12], s = 0.f;
    for (int j = 0; j < 12; j++){ e[j] = __expf(row[j] - m); s += e[j]; }
    float inv = 1.f / s;
    for (int j = 0; j < 12; j++) outB[h*144 + i*12 + j] = e[j] * inv;
  }
}

// ---------------------------------------------------------------------------
// Build fused GAT operator (or plain fW) in MFMA B-frag layout
// [nt][kt][64][8]. grid = nt*KT blocks x 64 threads.
// M[(j*Cin+k), (i*Cout+o)] = p[h(o),i,j] * W[k,o], h(o)=o/hdiv ; p==null -> W[k][n].
// ---------------------------------------------------------------------------
__global__ void k_prep_op(const float* __restrict__ W, const float* __restrict__ p,
                          int Cin, int Cout, int hdiv, int K, int KT, int N,
                          ushort* __restrict__ dst)
{
  int bI = blockIdx.x;
  int kt = bI % KT, nt = bI / KT;
  int l = threadIdx.x, ln = l & 15, q = l >> 4;
  int n = nt * 16 + ln;
  for (int j = 0; j < 8; j++){
    int k = kt * 32 + q * 8 + j;
    float v = 0.f;
    if (k < K && n < N){
      if (p){
        int jj = k / Cin, kk = k % Cin;
        int i = n / Cout, o = n % Cout;
        v = p[(o / hdiv) * 144 + i * 12 + jj] * W[kk * Cout + o];
      } else {
        v = W[k * Cout + n];
      }
    }
    dst[((long)bI * 64 + l) * 8 + j] = f2b(v);
  }
}

// ---------------------------------------------------------------------------
// Prep LSTM weight [576][144] -> frag layout [36][5][64][8] bf16 (K pad 160).
// grid (180, 7) x 64.
// ---------------------------------------------------------------------------
__global__ void k_prep_lstm(const float* W0, const float* W1, const float* W2,
                            const float* W3, const float* W4, const float* W5,
                            const float* W6, ushort* __restrict__ dstBase)
{
  const float* Wt[7] = {W0, W1, W2, W3, W4, W5, W6};
  const float* W = Wt[blockIdx.y];
  ushort* d = dstBase + (long)blockIdx.y * 92160;
  int bI = blockIdx.x;                 // ntile = bI/5, kt = bI%5
  int l = threadIdx.x, ln = l & 15, q = l >> 4;
  int n = (bI / 5) * 16 + ln;
  for (int j = 0; j < 8; j++){
    int k = (bI % 5) * 32 + q * 8 + j;
    float v = (k < 144) ? W[(long)n * 144 + k] : 0.f;
    d[((long)bI * 64 + l) * 8 + j] = f2b(v);
  }
}

// ---------------------------------------------------------------------------
// GAT layers 0+1 as fused-operator MFMA GEMMs. 512 thr, 128 rows/block.
// ---------------------------------------------------------------------------
__global__ __launch_bounds__(512) void k_gat01(
    const float* __restrict__ x, const ushort* __restrict__ M0f, const float* __restrict__ b0,
    const ushort* __restrict__ M1f, const float* __restrict__ b1,
    ushort* __restrict__ seq)
{
  __shared__ ushort xs[128 * 288];    // 73728 B (K pad 264->288; reused for h2 out)
  __shared__ ushort h1e[128 * 200];   // 51200 B (192 cols, stride 200)
  int t = threadIdx.x;
  long row0 = (long)blockIdx.x * 128;
  int w = t >> 6, l = t & 63, q = l >> 4, ln = l & 15;
  if (t < 384){
    int row = t / 3, seg = t % 3;
    *(uint4*)&xs[row * 288 + 264 + seg * 8] = make_uint4(0u, 0u, 0u, 0u);
  }
  for (int idx = t; idx < 8448; idx += 512){
    int row = idx / 66, c4 = idx % 66;
    float4 v = *(const float4*)&x[(row0 + row) * 264 + c4 * 4];
    ushort4 o; o.x = f2b(v.x); o.y = f2b(v.y); o.z = f2b(v.z); o.w = f2b(v.w);
    *(ushort4*)&xs[row * 288 + c4 * 4] = o;
  }
  int nta[2] = {w, (w < 4) ? 8 + w : -1};
  bfrag8 f0[2][9];
  #pragma unroll
  for (int ii = 0; ii < 2; ii++)
    if (nta[ii] >= 0)
      #pragma unroll
      for (int kt = 0; kt < 9; kt++)
        f0[ii][kt] = *(const bfrag8*)&M0f[((long)(nta[ii] * 9 + kt) * 64 + l) * 8];
  float bias0 = b0[ln];
  __syncthreads();
  for (int rb = 0; rb < 8; rb++){
    bfrag8 af[9];
    #pragma unroll
    for (int kt = 0; kt < 9; kt++)
      af[kt] = *(const bfrag8*)&xs[(rb * 16 + ln) * 288 + kt * 32 + q * 8];
    #pragma unroll
    for (int ii = 0; ii < 2; ii++){
      if (nta[ii] < 0) continue;
      ffrag4 acc = {bias0, bias0, bias0, bias0};
      #pragma unroll
      for (int kt = 0; kt < 9; kt++)
        acc = __builtin_amdgcn_mfma_f32_16x16x32_bf16(af[kt], f0[ii][kt], acc, 0, 0, 0);
      #pragma unroll
      for (int r = 0; r < 4; r++)
        h1e[(rb * 16 + q * 4 + r) * 200 + nta[ii] * 16 + ln] = f2b(elu_(acc[r]));
    }
  }
  int ntb[2] = {w, (w == 0) ? 8 : -1};
  bfrag8 f1[2][6];
  #pragma unroll
  for (int ii = 0; ii < 2; ii++)
    if (ntb[ii] >= 0)
      #pragma unroll
      for (int kt = 0; kt < 6; kt++)
        f1[ii][kt] = *(const bfrag8*)&M1f[((long)(ntb[ii] * 6 + kt) * 64 + l) * 8];
  __syncthreads();
  for (int rb = 0; rb < 8; rb++){
    bfrag8 af[6];
    #pragma unroll
    for (int kt = 0; kt < 6; kt++)
      af[kt] = *(const bfrag8*)&h1e[(rb * 16 + ln) * 200 + kt * 32 + q * 8];
    #pragma unroll
    for (int ii = 0; ii < 2; ii++){
      if (ntb[ii] < 0) continue;
      int n = ntb[ii] * 16 + ln;
      float bias = b1[n % 12];
      ffrag4 acc = {bias, bias, bias, bias};
      #pragma unroll
      for (int kt = 0; kt < 6; kt++)
        acc = __builtin_amdgcn_mfma_f32_16x16x32_bf16(af[kt], f1[ii][kt], acc, 0, 0, 0);
      #pragma unroll
      for (int r = 0; r < 4; r++)
        xs[(rb * 16 + q * 4 + r) * 144 + n] = f2b(elu_(acc[r]));
    }
  }
  __syncthreads();
  for (int i = t; i < 2304; i += 512)
    *(uint4*)&seq[row0 * 144 + (long)i * 8] = *(uint4*)&xs[i * 8];
}

// ---------------------------------------------------------------------------
// LSTM layer scan with fused input projection. 256 blocks x 576 threads.
// Each block owns 16 batch rows for all 24 steps; Wih/Whh B-frags in regs.
// ---------------------------------------------------------------------------
__global__ __launch_bounds__(576) void k_scan(
    const ushort* __restrict__ Xf,    // Wih frags [36][5][64][8] or null
    const ushort* __restrict__ Hf,    // Whh frags
    const ushort* __restrict__ seqin, // [98304][144] bf16 or null (zeros)
    const float* __restrict__ bih, const float* __restrict__ bhh,
    const ushort* __restrict__ h0,    // [4096][144] bf16 or null
    ushort* __restrict__ Y,           // [98304][144] bf16 or null
    ushort* __restrict__ hT)          // [4096][144] bf16 or null
{
  __shared__ ushort hl[16 * 160];
  __shared__ ushort xsb[2][16 * 160];
  int t = threadIdx.x, rbk = blockIdx.x;
  for (int i = t; i < 2560; i += 576){ hl[i] = 0; xsb[0][i] = 0; xsb[1][i] = 0; }
  __syncthreads();
  int r_cp = t / 36, ch_cp = t % 36;
  if (h0)
    *(ushort4*)&hl[r_cp * 160 + ch_cp * 4] =
        *(const ushort4*)&h0[((long)rbk * 16 + r_cp) * 144 + ch_cp * 4];
  int w = t / 64, l = t & 63, q = l >> 4, ln = l & 15;
  bfrag8 wh[4][5], wx[4][5];
  #pragma unroll
  for (int gt = 0; gt < 4; gt++)
    #pragma unroll
    for (int kt = 0; kt < 5; kt++){
      long fi = (((long)(gt * 9 + w) * 5 + kt) * 64 + l) * 8;
      wh[gt][kt] = *(const bfrag8*)&Hf[fi];
      if (Xf) wx[gt][kt] = *(const bfrag8*)&Xf[fi];
    }
  float bias[4];
  #pragma unroll
  for (int gt = 0; gt < 4; gt++){
    int n = gt * 144 + w * 16 + ln;
    bias[gt] = bih[n] + bhh[n];
  }
  ushort4 sv = make_ushort4(0, 0, 0, 0);
  if (seqin)
    sv = *(const ushort4*)&seqin[((long)rbk * 16 + r_cp) * 144 + ch_cp * 4];
  float c[4] = {0.f, 0.f, 0.f, 0.f};
  if (seqin) *(ushort4*)&xsb[0][r_cp * 160 + ch_cp * 4] = sv;
  __syncthreads();   // hl (zeros+h0) and xsb[0] visible
  for (int ts = 0; ts < 24; ts++){
    int cur = ts & 1;
    if (seqin && ts < 23)
      sv = *(const ushort4*)&seqin[(((long)(ts + 1) * 4096) + rbk * 16 + r_cp) * 144 + ch_cp * 4];
    bfrag8 ah[5], ax[5];
    #pragma unroll
    for (int kt = 0; kt < 5; kt++)
      ah[kt] = *(const bfrag8*)&hl[ln * 160 + kt * 32 + q * 8];
    if (seqin)
      #pragma unroll
      for (int kt = 0; kt < 5; kt++)
        ax[kt] = *(const bfrag8*)&xsb[cur][ln * 160 + kt * 32 + q * 8];
    ffrag4 acc[4];
    #pragma unroll
    for (int gt = 0; gt < 4; gt++){
      float b = bias[gt];
      acc[gt][0] = b; acc[gt][1] = b; acc[gt][2] = b; acc[gt][3] = b;
    }
    if (seqin)
      #pragma unroll
      for (int gt = 0; gt < 4; gt++)
        #pragma unroll
        for (int kt = 0; kt < 5; kt++)
          acc[gt] = __builtin_amdgcn_mfma_f32_16x16x32_bf16(ax[kt], wx[gt][kt], acc[gt], 0, 0, 0);
    #pragma unroll
    for (int gt = 0; gt < 4; gt++)
      #pragma unroll
      for (int kt = 0; kt < 5; kt++)
        acc[gt] = __builtin_amdgcn_mfma_f32_16x16x32_bf16(ah[kt], wh[gt][kt], acc[gt], 0, 0, 0);
    __syncthreads();   // all hl/xs reads complete
    ushort hb[4];
    #pragma unroll
    for (int r = 0; r < 4; r++){
      float iv = acc[0][r], fv = acc[1][r], gv = acc[2][r], ov = acc[3][r];
      float cn = sigm(fv) * c[r] + sigm(iv) * tanh_(gv);
      c[r] = cn;
      hb[r] = f2b(sigm(ov) * tanh_(cn));
    }
    #pragma unroll
    for (int r = 0; r < 4; r++)
      hl[(q * 4 + r) * 160 + w * 16 + ln] = hb[r];
    if (seqin && ts < 23)
      *(ushort4*)&xsb[cur ^ 1][r_cp * 160 + ch_cp * 4] = sv;
    __syncthreads();   // hl writes visible
    if (Y)
      *(ushort4*)&Y[(((long)ts * 4096) + rbk * 16 + r_cp) * 144 + ch_cp * 4] =
          *(const ushort4*)&hl[r_cp * 160 + ch_cp * 4];
  }
  if (hT)
    *(ushort4*)&hT[((long)rbk * 16 + r_cp) * 144 + ch_cp * 4] =
        *(const ushort4*)&hl[r_cp * 160 + ch_cp * 4];
}

// ---------------------------------------------------------------------------
// Tail: GAT3 -> GAT4 -> FC -> leaky -> fused MSE. 512 thr, 128 rows/block.
// ---------------------------------------------------------------------------
__global__ __launch_bounds__(512) void k_tail(
    const ushort* __restrict__ Ya, const ushort* __restrict__ M3f, const float* __restrict__ b3,
    const ushort* __restrict__ M4f, const float* __restrict__ b4,
    const ushort* __restrict__ fWt, const float* __restrict__ fb,
    const float* __restrict__ x, float* __restrict__ out)
{
  __shared__ ushort h3e[128 * 200];   // 51200
  __shared__ ushort bufB[128 * 288];  // 73728: ys (stride 160) then h4e (stride 288)
  __shared__ float psum[128 * 8];
  ushort* ys = bufB;
  ushort* h4e = bufB;
  int t = threadIdx.x;
  long row0 = (long)blockIdx.x * 128;
  int w = t >> 6, l = t & 63, q = l >> 4, ln = l & 15;
  if (t < 256){
    int row = t / 2, seg = t % 2;
    *(uint4*)&ys[row * 160 + 144 + seg * 8] = make_uint4(0u, 0u, 0u, 0u);
  }
  for (int idx = t; idx < 2304; idx += 512){
    int row = idx / 18, ch = idx % 18;
    *(uint4*)&ys[row * 160 + ch * 8] = *(const uint4*)&Ya[(row0 + row) * 144 + (long)ch * 8];
  }
  int nta[2] = {w, (w < 4) ? 8 + w : -1};
  bfrag8 f3[2][5];
  #pragma unroll
  for (int ii = 0; ii < 2; ii++)
    if (nta[ii] >= 0)
      #pragma unroll
      for (int kt = 0; kt < 5; kt++)
        f3[ii][kt] = *(const bfrag8*)&M3f[((long)(nta[ii] * 5 + kt) * 64 + l) * 8];
  float bias3 = b3[ln];
  __syncthreads();
  for (int rb = 0; rb < 8; rb++){
    bfrag8 af[5];
    #pragma unroll
    for (int kt = 0; kt < 5; kt++)
      af[kt] = *(const bfrag8*)&ys[(rb * 16 + ln) * 160 + kt * 32 + q * 8];
    #pragma unroll
    for (int ii = 0; ii < 2; ii++){
      if (nta[ii] < 0) continue;
      ffrag4 acc = {bias3, bias3, bias3, bias3};
      #pragma unroll
      for (int kt = 0; kt < 5; kt++)
        acc = __builtin_amdgcn_mfma_f32_16x16x32_bf16(af[kt], f3[ii][kt], acc, 0, 0, 0);
      #pragma unroll
      for (int r = 0; r < 4; r++)
        h3e[(rb * 16 + q * 4 + r) * 200 + nta[ii] * 16 + ln] = f2b(elu_(acc[r]));
    }
  }
  int ntb[3] = {2 * w, 2 * w + 1, (w < 2) ? 16 + w : -1};
  bfrag8 f4[3][6];
  #pragma unroll
  for (int ii = 0; ii < 3; ii++)
    if (ntb[ii] >= 0)
      #pragma unroll
      for (int kt = 0; kt < 6; kt++)
        f4[ii][kt] = *(const bfrag8*)&M4f[((long)(ntb[ii] * 6 + kt) * 64 + l) * 8];
  __syncthreads();   // all ys reads done; bufB becomes h4e
  for (int rb = 0; rb < 8; rb++){
    bfrag8 af[6];
    #pragma unroll
    for (int kt = 0; kt < 6; kt++)
      af[kt] = *(const bfrag8*)&h3e[(rb * 16 + ln) * 200 + kt * 32 + q * 8];
    #pragma unroll
    for (int ii = 0; ii < 3; ii++){
      if (ntb[ii] < 0) continue;
      int n = ntb[ii] * 16 + ln;
      float bias = b4[n % 24];
      ffrag4 acc = {bias, bias, bias, bias};
      #pragma unroll
      for (int kt = 0; kt < 6; kt++)
        acc = __builtin_amdgcn_mfma_f32_16x16x32_bf16(af[kt], f4[ii][kt], acc, 0, 0, 0);
      #pragma unroll
      for (int r = 0; r < 4; r++)
        h4e[(rb * 16 + q * 4 + r) * 288 + n] = f2b(elu_(acc[r]));
    }
  }
  int ntc[3] = {2 * w, 2 * w + 1, (w == 0) ? 16 : -1};
  bfrag8 f5[3][9];
  float bias5[3] = {0.f, 0.f, 0.f};
  #pragma unroll
  for (int ii = 0; ii < 3; ii++)
    if (ntc[ii] >= 0){
      #pragma unroll
      for (int kt = 0; kt < 9; kt++)
        f5[ii][kt] = *(const bfrag8*)&fWt[((long)(ntc[ii] * 9 + kt) * 64 + l) * 8];
      int n = ntc[ii] * 16 + ln;
      bias5[ii] = (n < 264) ? fb[n] : 0.f;
    }
  __syncthreads();
  for (int rb = 0; rb < 8; rb++){
    bfrag8 af[9];
    #pragma unroll
    for (int kt = 0; kt < 9; kt++)
      af[kt] = *(const bfrag8*)&h4e[(rb * 16 + ln) * 288 + kt * 32 + q * 8];
    float s4[4] = {0.f, 0.f, 0.f, 0.f};
    #pragma unroll
    for (int ii = 0; ii < 3; ii++){
      if (ntc[ii] < 0) continue;
      ffrag4 acc = {bias5[ii], bias5[ii], bias5[ii], bias5[ii]};
      #pragma unroll
      for (int kt = 0; kt < 9; kt++)
        acc = __builtin_amdgcn_mfma_f32_16x16x32_bf16(af[kt], f5[ii][kt], acc, 0, 0, 0);
      int n = ntc[ii] * 16 + ln;
      if (n < 264){
        #pragma unroll
        for (int r = 0; r < 4; r++){
          float v = acc[r];
          v = v > 0.f ? v : 0.01f * v;
          long row = row0 + rb * 16 + q * 4 + r;
          float d = x[row * 264 + n] - v;
          s4[r] += d * d;
        }
      }
    }
    #pragma unroll
    for (int off = 1; off < 16; off <<= 1){
      #pragma unroll
      for (int r = 0; r < 4; r++) s4[r] += __shfl_xor(s4[r], off, 16);
    }
    if (ln == 0){
      #pragma unroll
      for (int r = 0; r < 4; r++) psum[(rb * 16 + q * 4 + r) * 8 + w] = s4[r];
    }
  }
  __syncthreads();
  if (t < 128){
    float s = 0.f;
    for (int k = 0; k < 8; k++) s += psum[t * 8 + k];
    out[row0 + t] = s * (1.0f / 264.0f);
  }
}

// ---------------------------------------------------------------------------
extern "C" void kernel_launch(void* const* d_in, const int* in_sizes, int n_in,
                              void* d_out, int out_size, void* d_ws, size_t ws_size,
                              hipStream_t stream)
{
  const float* x     = (const float*)d_in[0];
  const float* gW0   = (const float*)d_in[1];
  const float* gb0   = (const float*)d_in[2];
  const float* ga0   = (const float*)d_in[3];
  const float* gW1   = (const float*)d_in[4];
  const float* gb1   = (const float*)d_in[5];
  const float* ga1   = (const float*)d_in[6];
  const float* eWih0 = (const float*)d_in[7];
  const float* eWhh0 = (const float*)d_in[8];
  const float* ebih0 = (const float*)d_in[9];
  const float* ebhh0 = (const float*)d_in[10];
  const float* eWih1 = (const float*)d_in[11];
  const float* eWhh1 = (const float*)d_in[12];
  const float* ebih1 = (const float*)d_in[13];
  const float* ebhh1 = (const float*)d_in[14];
  const float* dWhh0 = (const float*)d_in[16];
  const float* dbih0 = (const float*)d_in[17];
  const float* dbhh0 = (const float*)d_in[18];
  const float* dWih1 = (const float*)d_in[19];
  const float* dWhh1 = (const float*)d_in[20];
  const float* dbih1 = (const float*)d_in[21];
  const float* dbhh1 = (const float*)d_in[22];
  const float* gW3   = (const float*)d_in[23];
  const float* gb3   = (const float*)d_in[24];
  const float* ga3   = (const float*)d_in[25];
  const float* gW4   = (const float*)d_in[26];
  const float* gb4   = (const float*)d_in[27];
  const float* ga4   = (const float*)d_in[28];
  const float* fW    = (const float*)d_in[29];
  const float* fb    = (const float*)d_in[30];

  char* ws = (char*)d_ws;
  float*  probs0 = (float*)(ws + 0);
  float*  probs1 = (float*)(ws + 2304);
  float*  probs3 = (float*)(ws + 4608);
  float*  probs4 = (float*)(ws + 6912);
  ushort* M0f    = (ushort*)(ws + 9216);       // 110592 B
  ushort* M1f    = (ushort*)(ws + 119808);     // 55296 B
  ushort* M3f    = (ushort*)(ws + 175104);     // 61440 B
  ushort* M4f    = (ushort*)(ws + 236544);     // 110592 B
  ushort* fWt    = (ushort*)(ws + 347136);     // 156672 B
  ushort* lstmF  = (ushort*)(ws + 503808);     // 7 x 184320 B
  ushort* seq    = (ushort*)(ws + 1794048);    // 28311552 B
  ushort* Ya     = (ushort*)(ws + 30105600);   // 28311552 B
  ushort* Yb     = (ushort*)(ws + 58417152);   // 28311552 B
  ushort* hT0    = (ushort*)(ws + 86728704);   // 1179648 B
  ushort* hT1    = (ushort*)(ws + 87908352);   // 1179648 B
  float* out = (float*)d_out;

  // slots: 0 eWih0, 1 eWhh0, 2 eWih1, 3 eWhh1, 4 dWhh0, 5 dWih1, 6 dWhh1
  k_prep_lstm<<<dim3(180, 7), 64, 0, stream>>>(eWih0, eWhh0, eWih1, eWhh1,
                                               dWhh0, dWih1, dWhh1, lstmF);
  k_prep_op<<<153, 64, 0, stream>>>(fW, nullptr, 0, 264, 1, 288, 9, 264, fWt);
  k_probs<<<1, 576, 0, stream>>>(x, nullptr, 22,
                                 gW0, gb0, ga0, 16, 4,
                                 gW1, gb1, ga1, 12, 3,
                                 probs0, probs1);
  k_prep_op<<<108, 64, 0, stream>>>(gW0, probs0, 22, 16, 4, 264, 9, 192, M0f);
  k_prep_op<<<54, 64, 0, stream>>>(gW1, probs1, 16, 12, 3, 192, 6, 144, M1f);
  k_gat01<<<768, 512, 0, stream>>>(x, M0f, gb0, M1f, gb1, seq);

  // encoder L0
  k_scan<<<256, 576, 0, stream>>>(lstmF + 0L * 92160, lstmF + 1L * 92160, seq,
                                  ebih0, ebhh0, nullptr, Ya, hT0);
  // encoder L1 (only final h needed)
  k_scan<<<256, 576, 0, stream>>>(lstmF + 2L * 92160, lstmF + 3L * 92160, Ya,
                                  ebih1, ebhh1, nullptr, nullptr, hT1);
  // decoder L0 (zero input)
  k_scan<<<256, 576, 0, stream>>>(nullptr, lstmF + 4L * 92160, nullptr,
                                  dbih0, dbhh0, hT0, Yb, nullptr);
  // decoder L1
  k_scan<<<256, 576, 0, stream>>>(lstmF + 5L * 92160, lstmF + 6L * 92160, Yb,
                                  dbih1, dbhh1, hT1, Ya, nullptr);

  k_probs<<<1, 576, 0, stream>>>(nullptr, Ya, 12,
                                 gW3, gb3, ga3, 16, 4,
                                 gW4, gb4, ga4, 24, 6,
                                 probs3, probs4);
  k_prep_op<<<60, 64, 0, stream>>>(gW3, probs3, 12, 16, 4, 144, 5, 192, M3f);
  k_prep_op<<<108, 64, 0, stream>>>(gW4, probs4, 16, 24, 6, 192, 6, 288, M4f);
  k_tail<<<768, 512, 0, stream>>>(Ya, M3f, gb3, M4f, gb4, fWt, fb, x, out);
}

// Round 3
// 669.146 us; speedup vs baseline: 1.7188x; 1.7188x over previous
//
#include <hip/hip_runtime.h>

#define DI __device__ __forceinline__

typedef short bfrag8 __attribute__((ext_vector_type(8)));
typedef float ffrag4 __attribute__((ext_vector_type(4)));

DI ushort f2b(float f){
  union { float f; unsigned u; } v; v.f = f;
  unsigned u = v.u;
  u += 0x7FFF + ((u >> 16) & 1);   // round-to-nearest-even
  return (ushort)(u >> 16);
}
DI float b2f(ushort h){
  union { unsigned u; float f; } v; v.u = ((unsigned)h) << 16;
  return v.f;
}
DI float sigm(float x){ return 1.0f / (1.0f + __expf(-x)); }
DI float tanh_(float x){ return 1.0f - 2.0f / (1.0f + __expf(2.0f * x)); }
DI float elu_(float x){ return x > 0.f ? x : __expf(x) - 1.f; }

// ---------------------------------------------------------------------------
// Tiny kernel: attention probs for a pair of GAT layers from sample 0.
// 1 block x 576 threads.
// ---------------------------------------------------------------------------
__global__ void k_probs(const float* xf, const ushort* xb, int in_c,
                        const float* W1, const float* b1, const float* a1, int hc1, int c1,
                        const float* W2, const float* b2, const float* a2, int hc2, int c2,
                        float* outA, float* outB)
{
  __shared__ float xs[12 * 22];
  __shared__ float h1[12 * 16];
  __shared__ float lg[4 * 144];
  __shared__ float pr[4 * 144];
  __shared__ float h1e[12 * 16];
  __shared__ float h2[12 * 24];
  const int t = threadIdx.x;
  const unsigned adj[12] = {0xC21u,0x482u,0x844u,0x048u,0x030u,0x031u,
                            0x44Cu,0x282u,0xF00u,0x780u,0xF43u,0xD05u};
  if (t < 12 * in_c){
    if (xf) xs[t] = xf[t];
    else    xs[t] = b2f(xb[t]);
  }
  __syncthreads();
  if (t < 12 * hc1){
    int i = t / hc1, o = t % hc1;
    float v = b1[o];
    for (int k = 0; k < in_c; k++) v += xs[i * in_c + k] * W1[k * hc1 + o];
    h1[t] = v;
  }
  __syncthreads();
  {
    int h = t / 144, ij = t % 144, i = ij / 12, j = ij % 12;
    float v;
    if ((adj[i] >> j) & 1){
      v = 0.f;
      for (int c = 0; c < c1; c++)
        v += a1[h*2*c1 + c] * h1[i*hc1 + h*c1 + c] + a1[h*2*c1 + c1 + c] * h1[j*hc1 + h*c1 + c];
      v = v > 0.f ? v : 0.2f * v;
    } else v = -9e15f;
    lg[t] = v;
  }
  __syncthreads();
  if (t < 48){
    int h = t / 12, i = t % 12;
    const float* row = &lg[h*144 + i*12];
    float m = row[0];
    for (int j = 1; j < 12; j++) m = fmaxf(m, row[j]);
    float e[12], s = 0.f;
    for (int j = 0; j < 12; j++){ e[j] = __expf(row[j] - m); s += e[j]; }
    float inv = 1.f / s;
    for (int j = 0; j < 12; j++){
      float p = e[j] * inv;
      pr[h*144 + i*12 + j] = p;
      outA[h*144 + i*12 + j] = p;
    }
  }
  __syncthreads();
  if (t < 12 * hc1){
    int i = t / hc1, o = t % hc1, h = o / c1;
    float v = 0.f;
    for (int j = 0; j < 12; j++) v += pr[h*144 + i*12 + j] * h1[j*hc1 + o];
    h1e[t] = elu_(v);
  }
  __syncthreads();
  if (t < 12 * hc2){
    int i = t / hc2, o = t % hc2;
    float v = b2[o];
    for (int k = 0; k < hc1; k++) v += h1e[i*hc1 + k] * W2[k*hc2 + o];
    h2[t] = v;
  }
  __syncthreads();
  {
    int h = t / 144, ij = t % 144, i = ij / 12, j = ij % 12;
    float v;
    if ((adj[i] >> j) & 1){
      v = 0.f;
      for (int c = 0; c < c2; c++)
        v += a2[h*2*c2 + c] * h2[i*hc2 + h*c2 + c] + a2[h*2*c2 + c2 + c] * h2[j*hc2 + h*c2 + c];
      v = v > 0.f ? v : 0.2f * v;
    } else v = -9e15f;
    lg[t] = v;
  }
  __syncthreads();
  if (t < 48){
    int h = t / 12, i = t % 12;
    const float* row = &lg[h*144 + i*12];
    float m = row[0];
    for (int j = 1; j < 12; j++) m = fmaxf(m, row[j]);
    float e[12], s = 0.f;
    for (int j = 0; j < 12; j++){ e[j] = __expf(row[j] - m); s += e[j]; }
    float inv = 1.f / s;
    for (int j = 0; j < 12; j++) outB[h*144 + i*12 + j] = e[j] * inv;
  }
}

// ---------------------------------------------------------------------------
// Build fused GAT operator (or plain fW) in MFMA B-frag layout
// [nt][kt][64][8]. grid = nt*KT blocks x 64 threads.
// ---------------------------------------------------------------------------
__global__ void k_prep_op(const float* __restrict__ W, const float* __restrict__ p,
                          int Cin, int Cout, int hdiv, int K, int KT, int N,
                          ushort* __restrict__ dst)
{
  int bI = blockIdx.x;
  int kt = bI % KT, nt = bI / KT;
  int l = threadIdx.x, ln = l & 15, q = l >> 4;
  int n = nt * 16 + ln;
  for (int j = 0; j < 8; j++){
    int k = kt * 32 + q * 8 + j;
    float v = 0.f;
    if (k < K && n < N){
      if (p){
        int jj = k / Cin, kk = k % Cin;
        int i = n / Cout, o = n % Cout;
        v = p[(o / hdiv) * 144 + i * 12 + jj] * W[kk * Cout + o];
      } else {
        v = W[k * Cout + n];
      }
    }
    dst[((long)bI * 64 + l) * 8 + j] = f2b(v);
  }
}

// ---------------------------------------------------------------------------
// Prep LSTM weights -> task-frag layout. Task tau in [0,72): tau<36 -> Whh
// tile, tau>=36 -> Wih tile (tt=tau-36). Per task 5 K-frags (K pad 144->160).
// dst element layout per combo: [ntau*5][64][8]. grid dim3(360,4) x 64.
// combos: 0 encL0(72), 1 encL1(72), 2 decL0(36, Whh only), 3 decL1(72).
// ---------------------------------------------------------------------------
__global__ void k_prep_lstm(const float* eWih0, const float* eWhh0,
                            const float* eWih1, const float* eWhh1,
                            const float* dWhh0,
                            const float* dWih1, const float* dWhh1,
                            ushort* __restrict__ dstBase)
{
  int combo = blockIdx.y;
  const float* Wh; const float* Wx; long off; int ntau;
  if (combo == 0){ Wh = eWhh0; Wx = eWih0; off = 0;      ntau = 72; }
  else if (combo == 1){ Wh = eWhh1; Wx = eWih1; off = 184320; ntau = 72; }
  else if (combo == 2){ Wh = dWhh0; Wx = dWhh0; off = 368640; ntau = 36; }
  else { Wh = dWhh1; Wx = dWih1; off = 460800; ntau = 72; }
  int bI = blockIdx.x;                 // tau*5 + kt
  int tau = bI / 5, kt = bI % 5;
  if (tau >= ntau) return;
  const float* W = (tau < 36) ? Wh : Wx;
  int tt = (tau < 36) ? tau : tau - 36;
  int gt = tt / 9, ct = tt % 9;
  int l = threadIdx.x, ln = l & 15, q = l >> 4;
  int n = gt * 144 + ct * 16 + ln;
  ushort* d = dstBase + off;
  for (int j = 0; j < 8; j++){
    int k = kt * 32 + q * 8 + j;
    float v = (k < 144) ? W[(long)n * 144 + k] : 0.f;
    d[((long)bI * 64 + l) * 8 + j] = f2b(v);
  }
}

// ---------------------------------------------------------------------------
// GAT layers 0+1 as fused-operator MFMA GEMMs. 512 thr, 128 rows/block.
// ---------------------------------------------------------------------------
__global__ __launch_bounds__(512) void k_gat01(
    const float* __restrict__ x, const ushort* __restrict__ M0f, const float* __restrict__ b0,
    const ushort* __restrict__ M1f, const float* __restrict__ b1,
    ushort* __restrict__ seq)
{
  __shared__ ushort xs[128 * 288];
  __shared__ ushort h1e[128 * 200];
  int t = threadIdx.x;
  long row0 = (long)blockIdx.x * 128;
  int w = t >> 6, l = t & 63, q = l >> 4, ln = l & 15;
  if (t < 384){
    int row = t / 3, seg = t % 3;
    *(uint4*)&xs[row * 288 + 264 + seg * 8] = make_uint4(0u, 0u, 0u, 0u);
  }
  for (int idx = t; idx < 8448; idx += 512){
    int row = idx / 66, c4 = idx % 66;
    float4 v = *(const float4*)&x[(row0 + row) * 264 + c4 * 4];
    ushort4 o; o.x = f2b(v.x); o.y = f2b(v.y); o.z = f2b(v.z); o.w = f2b(v.w);
    *(ushort4*)&xs[row * 288 + c4 * 4] = o;
  }
  int nta[2] = {w, (w < 4) ? 8 + w : -1};
  bfrag8 f0[2][9];
  #pragma unroll
  for (int ii = 0; ii < 2; ii++)
    if (nta[ii] >= 0)
      #pragma unroll
      for (int kt = 0; kt < 9; kt++)
        f0[ii][kt] = *(const bfrag8*)&M0f[((long)(nta[ii] * 9 + kt) * 64 + l) * 8];
  float bias0 = b0[ln];
  __syncthreads();
  for (int rb = 0; rb < 8; rb++){
    bfrag8 af[9];
    #pragma unroll
    for (int kt = 0; kt < 9; kt++)
      af[kt] = *(const bfrag8*)&xs[(rb * 16 + ln) * 288 + kt * 32 + q * 8];
    #pragma unroll
    for (int ii = 0; ii < 2; ii++){
      if (nta[ii] < 0) continue;
      ffrag4 acc = {bias0, bias0, bias0, bias0};
      #pragma unroll
      for (int kt = 0; kt < 9; kt++)
        acc = __builtin_amdgcn_mfma_f32_16x16x32_bf16(af[kt], f0[ii][kt], acc, 0, 0, 0);
      #pragma unroll
      for (int r = 0; r < 4; r++)
        h1e[(rb * 16 + q * 4 + r) * 200 + nta[ii] * 16 + ln] = f2b(elu_(acc[r]));
    }
  }
  int ntb[2] = {w, (w == 0) ? 8 : -1};
  bfrag8 f1[2][6];
  #pragma unroll
  for (int ii = 0; ii < 2; ii++)
    if (ntb[ii] >= 0)
      #pragma unroll
      for (int kt = 0; kt < 6; kt++)
        f1[ii][kt] = *(const bfrag8*)&M1f[((long)(ntb[ii] * 6 + kt) * 64 + l) * 8];
  __syncthreads();
  for (int rb = 0; rb < 8; rb++){
    bfrag8 af[6];
    #pragma unroll
    for (int kt = 0; kt < 6; kt++)
      af[kt] = *(const bfrag8*)&h1e[(rb * 16 + ln) * 200 + kt * 32 + q * 8];
    #pragma unroll
    for (int ii = 0; ii < 2; ii++){
      if (ntb[ii] < 0) continue;
      int n = ntb[ii] * 16 + ln;
      float bias = b1[n % 12];
      ffrag4 acc = {bias, bias, bias, bias};
      #pragma unroll
      for (int kt = 0; kt < 6; kt++)
        acc = __builtin_amdgcn_mfma_f32_16x16x32_bf16(af[kt], f1[ii][kt], acc, 0, 0, 0);
      #pragma unroll
      for (int r = 0; r < 4; r++)
        xs[(rb * 16 + q * 4 + r) * 144 + n] = f2b(elu_(acc[r]));
    }
  }
  __syncthreads();
  for (int i = t; i < 2304; i += 512)
    *(uint4*)&seq[row0 * 144 + (long)i * 8] = *(uint4*)&xs[i * 8];
}

// ---------------------------------------------------------------------------
// LSTM layer scan, 256 blocks x 512 threads (8 waves, 2/SIMD => VGPR<=256).
// 16 batch rows/block x 24 steps. 72 tasks (36 h-proj + 36 x-proj), 9/wave,
// full weight-frag register residency. Preacts go through LDS P/Px; a
// decoupled elementwise phase does the i/f/g/o update (bias via LDS).
// ---------------------------------------------------------------------------
template<bool HASX>
__global__ __launch_bounds__(512, 2) void k_scan(
    const ushort* __restrict__ Wf,    // [ntau*5][64][8] frags
    const ushort* __restrict__ seqin, // [24*4096][144] bf16 or null
    const float* __restrict__ bih, const float* __restrict__ bhh,
    const ushort* __restrict__ h0,    // [4096][144] bf16 or null
    ushort* __restrict__ Y,           // [98304][144] bf16 or null
    ushort* __restrict__ hT)          // [4096][144] bf16 or null
{
  constexpr int NT = HASX ? 9 : 5;
  __shared__ ushort hl[16 * 168];                    // h, K-padded, stride 168
  __shared__ float P[(HASX ? 2 : 1) * 9216];         // preacts [gt][col][row16]
  __shared__ float bsh[576];
  int t = threadIdx.x, rbk = blockIdx.x;
  int w = t >> 6, l = t & 63, q = l >> 4, ln = l & 15;
  if (t < 336){
    int row = t / 21, ch = t % 21;
    uint4 z = make_uint4(0u, 0u, 0u, 0u);
    if (h0 && ch < 18) z = *(const uint4*)&h0[((long)rbk * 16 + row) * 144 + ch * 8];
    *(uint4*)&hl[row * 168 + ch * 8] = z;
  }
  for (int i = t; i < 576; i += 512) bsh[i] = bih[i] + bhh[i];
  // weight fragments: task tau = w + i*8
  bfrag8 wf[NT][5];
  #pragma unroll
  for (int i = 0; i < NT; i++){
    int tau = w + i * 8;
    int tc = (HASX || tau < 36) ? tau : 0;
    #pragma unroll
    for (int kt = 0; kt < 5; kt++)
      wf[i][kt] = *(const bfrag8*)&Wf[((long)(tc * 5 + kt) * 64 + l) * 8];
  }
  float cst[5] = {0.f, 0.f, 0.f, 0.f, 0.f};
  __syncthreads();
  for (int ts = 0; ts < 24; ts++){
    bfrag8 ah[5];
    #pragma unroll
    for (int kt = 0; kt < 5; kt++)
      ah[kt] = *(const bfrag8*)&hl[ln * 168 + kt * 32 + q * 8];
    bfrag8 ax[5];
    if (HASX){
      const ushort* xr = &seqin[(((long)ts * 4096) + (long)rbk * 16 + ln) * 144];
      #pragma unroll
      for (int kt = 0; kt < 5; kt++)
        ax[kt] = *(const bfrag8*)&xr[kt * 32 + q * 8];   // cols>=144 read junk * zero-B
    }
    #pragma unroll
    for (int i = 0; i < NT; i++){
      int tau = w + i * 8;
      if (!HASX && tau >= 36) continue;
      ffrag4 acc = {0.f, 0.f, 0.f, 0.f};
      if (HASX && tau >= 36){
        #pragma unroll
        for (int kt = 0; kt < 5; kt++)
          acc = __builtin_amdgcn_mfma_f32_16x16x32_bf16(ax[kt], wf[i][kt], acc, 0, 0, 0);
        int tt = tau - 36;
        *(float4*)&P[9216 + ((tt / 9) * 144 + (tt % 9) * 16 + ln) * 16 + q * 4] = *(float4*)&acc;
      } else {
        #pragma unroll
        for (int kt = 0; kt < 5; kt++)
          acc = __builtin_amdgcn_mfma_f32_16x16x32_bf16(ah[kt], wf[i][kt], acc, 0, 0, 0);
        *(float4*)&P[((tau / 9) * 144 + (tau % 9) * 16 + ln) * 16 + q * 4] = *(float4*)&acc;
      }
    }
    __syncthreads();   // P complete; all hl reads done
    #pragma unroll
    for (int j = 0; j < 5; j++){
      int cell = t + j * 512;
      if (cell < 2304){
        int col = cell >> 4, row = cell & 15;
        int base = col * 16 + row;
        float iv = P[base], fv = P[2304 + base], gv = P[4608 + base], ov = P[6912 + base];
        if (HASX){
          iv += P[9216 + base]; fv += P[9216 + 2304 + base];
          gv += P[9216 + 4608 + base]; ov += P[9216 + 6912 + base];
        }
        iv += bsh[col]; fv += bsh[144 + col]; gv += bsh[288 + col]; ov += bsh[432 + col];
        float cn = sigm(fv) * cst[j] + sigm(iv) * tanh_(gv);
        cst[j] = cn;
        hl[row * 168 + col] = f2b(sigm(ov) * tanh_(cn));
      }
    }
    __syncthreads();   // hl updated; P free for next step
    if (Y && t < 288){
      int row = t / 18, ch = t % 18;
      *(uint4*)&Y[(((long)ts * 4096) + (long)rbk * 16 + row) * 144 + ch * 8] =
          *(uint4*)&hl[row * 168 + ch * 8];
    }
  }
  if (hT && t < 288){
    int row = t / 18, ch = t % 18;
    *(uint4*)&hT[((long)rbk * 16 + row) * 144 + ch * 8] = *(uint4*)&hl[row * 168 + ch * 8];
  }
}

// ---------------------------------------------------------------------------
// Tail: GAT3 -> GAT4 -> FC -> leaky -> fused MSE. 512 thr, 128 rows/block.
// ---------------------------------------------------------------------------
__global__ __launch_bounds__(512) void k_tail(
    const ushort* __restrict__ Ya, const ushort* __restrict__ M3f, const float* __restrict__ b3,
    const ushort* __restrict__ M4f, const float* __restrict__ b4,
    const ushort* __restrict__ fWt, const float* __restrict__ fb,
    const float* __restrict__ x, float* __restrict__ out)
{
  __shared__ ushort h3e[128 * 200];
  __shared__ ushort bufB[128 * 288];
  __shared__ float psum[128 * 8];
  ushort* ys = bufB;
  ushort* h4e = bufB;
  int t = threadIdx.x;
  long row0 = (long)blockIdx.x * 128;
  int w = t >> 6, l = t & 63, q = l >> 4, ln = l & 15;
  if (t < 256){
    int row = t / 2, seg = t % 2;
    *(uint4*)&ys[row * 160 + 144 + seg * 8] = make_uint4(0u, 0u, 0u, 0u);
  }
  for (int idx = t; idx < 2304; idx += 512){
    int row = idx / 18, ch = idx % 18;
    *(uint4*)&ys[row * 160 + ch * 8] = *(const uint4*)&Ya[(row0 + row) * 144 + (long)ch * 8];
  }
  int nta[2] = {w, (w < 4) ? 8 + w : -1};
  bfrag8 f3[2][5];
  #pragma unroll
  for (int ii = 0; ii < 2; ii++)
    if (nta[ii] >= 0)
      #pragma unroll
      for (int kt = 0; kt < 5; kt++)
        f3[ii][kt] = *(const bfrag8*)&M3f[((long)(nta[ii] * 5 + kt) * 64 + l) * 8];
  float bias3 = b3[ln];
  __syncthreads();
  for (int rb = 0; rb < 8; rb++){
    bfrag8 af[5];
    #pragma unroll
    for (int kt = 0; kt < 5; kt++)
      af[kt] = *(const bfrag8*)&ys[(rb * 16 + ln) * 160 + kt * 32 + q * 8];
    #pragma unroll
    for (int ii = 0; ii < 2; ii++){
      if (nta[ii] < 0) continue;
      ffrag4 acc = {bias3, bias3, bias3, bias3};
      #pragma unroll
      for (int kt = 0; kt < 5; kt++)
        acc = __builtin_amdgcn_mfma_f32_16x16x32_bf16(af[kt], f3[ii][kt], acc, 0, 0, 0);
      #pragma unroll
      for (int r = 0; r < 4; r++)
        h3e[(rb * 16 + q * 4 + r) * 200 + nta[ii] * 16 + ln] = f2b(elu_(acc[r]));
    }
  }
  int ntb[3] = {2 * w, 2 * w + 1, (w < 2) ? 16 + w : -1};
  bfrag8 f4[3][6];
  #pragma unroll
  for (int ii = 0; ii < 3; ii++)
    if (ntb[ii] >= 0)
      #pragma unroll
      for (int kt = 0; kt < 6; kt++)
        f4[ii][kt] = *(const bfrag8*)&M4f[((long)(ntb[ii] * 6 + kt) * 64 + l) * 8];
  __syncthreads();
  for (int rb = 0; rb < 8; rb++){
    bfrag8 af[6];
    #pragma unroll
    for (int kt = 0; kt < 6; kt++)
      af[kt] = *(const bfrag8*)&h3e[(rb * 16 + ln) * 200 + kt * 32 + q * 8];
    #pragma unroll
    for (int ii = 0; ii < 3; ii++){
      if (ntb[ii] < 0) continue;
      int n = ntb[ii] * 16 + ln;
      float bias = b4[n % 24];
      ffrag4 acc = {bias, bias, bias, bias};
      #pragma unroll
      for (int kt = 0; kt < 6; kt++)
        acc = __builtin_amdgcn_mfma_f32_16x16x32_bf16(af[kt], f4[ii][kt], acc, 0, 0, 0);
      #pragma unroll
      for (int r = 0; r < 4; r++)
        h4e[(rb * 16 + q * 4 + r) * 288 + n] = f2b(elu_(acc[r]));
    }
  }
  int ntc[3] = {2 * w, 2 * w + 1, (w == 0) ? 16 : -1};
  bfrag8 f5[3][9];
  float bias5[3] = {0.f, 0.f, 0.f};
  #pragma unroll
  for (int ii = 0; ii < 3; ii++)
    if (ntc[ii] >= 0){
      #pragma unroll
      for (int kt = 0; kt < 9; kt++)
        f5[ii][kt] = *(const bfrag8*)&fWt[((long)(ntc[ii] * 9 + kt) * 64 + l) * 8];
      int n = ntc[ii] * 16 + ln;
      bias5[ii] = (n < 264) ? fb[n] : 0.f;
    }
  __syncthreads();
  for (int rb = 0; rb < 8; rb++){
    bfrag8 af[9];
    #pragma unroll
    for (int kt = 0; kt < 9; kt++)
      af[kt] = *(const bfrag8*)&h4e[(rb * 16 + ln) * 288 + kt * 32 + q * 8];
    float s4[4] = {0.f, 0.f, 0.f, 0.f};
    #pragma unroll
    for (int ii = 0; ii < 3; ii++){
      if (ntc[ii] < 0) continue;
      ffrag4 acc = {bias5[ii], bias5[ii], bias5[ii], bias5[ii]};
      #pragma unroll
      for (int kt = 0; kt < 9; kt++)
        acc = __builtin_amdgcn_mfma_f32_16x16x32_bf16(af[kt], f5[ii][kt], acc, 0, 0, 0);
      int n = ntc[ii] * 16 + ln;
      if (n < 264){
        #pragma unroll
        for (int r = 0; r < 4; r++){
          float v = acc[r];
          v = v > 0.f ? v : 0.01f * v;
          long row = row0 + rb * 16 + q * 4 + r;
          float d = x[row * 264 + n] - v;
          s4[r] += d * d;
        }
      }
    }
    #pragma unroll
    for (int off = 1; off < 16; off <<= 1){
      #pragma unroll
      for (int r = 0; r < 4; r++) s4[r] += __shfl_xor(s4[r], off, 16);
    }
    if (ln == 0){
      #pragma unroll
      for (int r = 0; r < 4; r++) psum[(rb * 16 + q * 4 + r) * 8 + w] = s4[r];
    }
  }
  __syncthreads();
  if (t < 128){
    float s = 0.f;
    for (int k = 0; k < 8; k++) s += psum[t * 8 + k];
    out[row0 + t] = s * (1.0f / 264.0f);
  }
}

// ---------------------------------------------------------------------------
extern "C" void kernel_launch(void* const* d_in, const int* in_sizes, int n_in,
                              void* d_out, int out_size, void* d_ws, size_t ws_size,
                              hipStream_t stream)
{
  const float* x     = (const float*)d_in[0];
  const float* gW0   = (const float*)d_in[1];
  const float* gb0   = (const float*)d_in[2];
  const float* ga0   = (const float*)d_in[3];
  const float* gW1   = (const float*)d_in[4];
  const float* gb1   = (const float*)d_in[5];
  const float* ga1   = (const float*)d_in[6];
  const float* eWih0 = (const float*)d_in[7];
  const float* eWhh0 = (const float*)d_in[8];
  const float* ebih0 = (const float*)d_in[9];
  const float* ebhh0 = (const float*)d_in[10];
  const float* eWih1 = (const float*)d_in[11];
  const float* eWhh1 = (const float*)d_in[12];
  const float* ebih1 = (const float*)d_in[13];
  const float* ebhh1 = (const float*)d_in[14];
  const float* dWhh0 = (const float*)d_in[16];
  const float* dbih0 = (const float*)d_in[17];
  const float* dbhh0 = (const float*)d_in[18];
  const float* dWih1 = (const float*)d_in[19];
  const float* dWhh1 = (const float*)d_in[20];
  const float* dbih1 = (const float*)d_in[21];
  const float* dbhh1 = (const float*)d_in[22];
  const float* gW3   = (const float*)d_in[23];
  const float* gb3   = (const float*)d_in[24];
  const float* ga3   = (const float*)d_in[25];
  const float* gW4   = (const float*)d_in[26];
  const float* gb4   = (const float*)d_in[27];
  const float* ga4   = (const float*)d_in[28];
  const float* fW    = (const float*)d_in[29];
  const float* fb    = (const float*)d_in[30];

  char* ws = (char*)d_ws;
  float*  probs0 = (float*)(ws + 0);
  float*  probs1 = (float*)(ws + 2304);
  float*  probs3 = (float*)(ws + 4608);
  float*  probs4 = (float*)(ws + 6912);
  ushort* M0f    = (ushort*)(ws + 9216);       // 110592 B
  ushort* M1f    = (ushort*)(ws + 119808);     // 55296 B
  ushort* M3f    = (ushort*)(ws + 175104);     // 61440 B
  ushort* M4f    = (ushort*)(ws + 236544);     // 110592 B
  ushort* fWt    = (ushort*)(ws + 347136);     // 156672 B
  ushort* lstmF  = (ushort*)(ws + 503808);     // 1290240 B
  ushort* seq    = (ushort*)(ws + 1794048);    // 28311552 B
  ushort* Ya     = (ushort*)(ws + 30105600);   // 28311552 B
  ushort* Yb     = (ushort*)(ws + 58417152);   // 28311552 B
  ushort* hT0    = (ushort*)(ws + 86728704);   // 1179648 B
  ushort* hT1    = (ushort*)(ws + 87908352);   // 1179648 B
  float* out = (float*)d_out;

  k_prep_lstm<<<dim3(360, 4), 64, 0, stream>>>(eWih0, eWhh0, eWih1, eWhh1,
                                               dWhh0, dWih1, dWhh1, lstmF);
  k_prep_op<<<153, 64, 0, stream>>>(fW, nullptr, 0, 264, 1, 288, 9, 264, fWt);
  k_probs<<<1, 576, 0, stream>>>(x, nullptr, 22,
                                 gW0, gb0, ga0, 16, 4,
                                 gW1, gb1, ga1, 12, 3,
                                 probs0, probs1);
  k_prep_op<<<108, 64, 0, stream>>>(gW0, probs0, 22, 16, 4, 264, 9, 192, M0f);
  k_prep_op<<<54, 64, 0, stream>>>(gW1, probs1, 16, 12, 3, 192, 6, 144, M1f);
  k_gat01<<<768, 512, 0, stream>>>(x, M0f, gb0, M1f, gb1, seq);

  // encoder L0
  k_scan<true><<<256, 512, 0, stream>>>(lstmF + 0L,      seq, ebih0, ebhh0, nullptr, Ya, hT0);
  // encoder L1 (only final h needed)
  k_scan<true><<<256, 512, 0, stream>>>(lstmF + 184320L, Ya, ebih1, ebhh1, nullptr, nullptr, hT1);
  // decoder L0 (zero input)
  k_scan<false><<<256, 512, 0, stream>>>(lstmF + 368640L, nullptr, dbih0, dbhh0, hT0, Yb, nullptr);
  // decoder L1
  k_scan<true><<<256, 512, 0, stream>>>(lstmF + 460800L, Yb, dbih1, dbhh1, hT1, Ya, nullptr);

  k_probs<<<1, 576, 0, stream>>>(nullptr, Ya, 12,
                                 gW3, gb3, ga3, 16, 4,
                                 gW4, gb4, ga4, 24, 6,
                                 probs3, probs4);
  k_prep_op<<<60, 64, 0, stream>>>(gW3, probs3, 12, 16, 4, 144, 5, 192, M3f);
  k_prep_op<<<108, 64, 0, stream>>>(gW4, probs4, 16, 24, 6, 192, 6, 288, M4f);
  k_tail<<<768, 512, 0, stream>>>(Ya, M3f, gb3, M4f, gb4, fWt, fb, x, out);
}

// Round 4
// 598.214 us; speedup vs baseline: 1.9225x; 1.1186x over previous
//
#include <hip/hip_runtime.h>

#define DI __device__ __forceinline__

typedef short bfrag8 __attribute__((ext_vector_type(8)));
typedef float ffrag4 __attribute__((ext_vector_type(4)));

DI ushort f2b(float f){
  union { float f; unsigned u; } v; v.f = f;
  unsigned u = v.u;
  u += 0x7FFF + ((u >> 16) & 1);   // round-to-nearest-even
  return (ushort)(u >> 16);
}
DI float b2f(ushort h){
  union { unsigned u; float f; } v; v.u = ((unsigned)h) << 16;
  return v.f;
}
DI float sigm(float x){ return 1.0f / (1.0f + __expf(-x)); }
DI float tanh_(float x){ return 1.0f - 2.0f / (1.0f + __expf(2.0f * x)); }
DI float elu_(float x){ return x > 0.f ? x : __expf(x) - 1.f; }

// ---------------------------------------------------------------------------
// Tiny kernel: attention probs for a pair of GAT layers from sample 0.
// 1 block x 576 threads.
// ---------------------------------------------------------------------------
__global__ void k_probs(const float* xf, const ushort* xb, int in_c,
                        const float* W1, const float* b1, const float* a1, int hc1, int c1,
                        const float* W2, const float* b2, const float* a2, int hc2, int c2,
                        float* outA, float* outB)
{
  __shared__ float xs[12 * 22];
  __shared__ float h1[12 * 16];
  __shared__ float lg[4 * 144];
  __shared__ float pr[4 * 144];
  __shared__ float h1e[12 * 16];
  __shared__ float h2[12 * 24];
  const int t = threadIdx.x;
  const unsigned adj[12] = {0xC21u,0x482u,0x844u,0x048u,0x030u,0x031u,
                            0x44Cu,0x282u,0xF00u,0x780u,0xF43u,0xD05u};
  if (t < 12 * in_c){
    if (xf) xs[t] = xf[t];
    else    xs[t] = b2f(xb[t]);
  }
  __syncthreads();
  if (t < 12 * hc1){
    int i = t / hc1, o = t % hc1;
    float v = b1[o];
    for (int k = 0; k < in_c; k++) v += xs[i * in_c + k] * W1[k * hc1 + o];
    h1[t] = v;
  }
  __syncthreads();
  {
    int h = t / 144, ij = t % 144, i = ij / 12, j = ij % 12;
    float v;
    if ((adj[i] >> j) & 1){
      v = 0.f;
      for (int c = 0; c < c1; c++)
        v += a1[h*2*c1 + c] * h1[i*hc1 + h*c1 + c] + a1[h*2*c1 + c1 + c] * h1[j*hc1 + h*c1 + c];
      v = v > 0.f ? v : 0.2f * v;
    } else v = -9e15f;
    lg[t] = v;
  }
  __syncthreads();
  if (t < 48){
    int h = t / 12, i = t % 12;
    const float* row = &lg[h*144 + i*12];
    float m = row[0];
    for (int j = 1; j < 12; j++) m = fmaxf(m, row[j]);
    float e[12], s = 0.f;
    for (int j = 0; j < 12; j++){ e[j] = __expf(row[j] - m); s += e[j]; }
    float inv = 1.f / s;
    for (int j = 0; j < 12; j++){
      float p = e[j] * inv;
      pr[h*144 + i*12 + j] = p;
      outA[h*144 + i*12 + j] = p;
    }
  }
  __syncthreads();
  if (t < 12 * hc1){
    int i = t / hc1, o = t % hc1, h = o / c1;
    float v = 0.f;
    for (int j = 0; j < 12; j++) v += pr[h*144 + i*12 + j] * h1[j*hc1 + o];
    h1e[t] = elu_(v);
  }
  __syncthreads();
  if (t < 12 * hc2){
    int i = t / hc2, o = t % hc2;
    float v = b2[o];
    for (int k = 0; k < hc1; k++) v += h1e[i*hc1 + k] * W2[k*hc2 + o];
    h2[t] = v;
  }
  __syncthreads();
  {
    int h = t / 144, ij = t % 144, i = ij / 12, j = ij % 12;
    float v;
    if ((adj[i] >> j) & 1){
      v = 0.f;
      for (int c = 0; c < c2; c++)
        v += a2[h*2*c2 + c] * h2[i*hc2 + h*c2 + c] + a2[h*2*c2 + c2 + c] * h2[j*hc2 + h*c2 + c];
      v = v > 0.f ? v : 0.2f * v;
    } else v = -9e15f;
    lg[t] = v;
  }
  __syncthreads();
  if (t < 48){
    int h = t / 12, i = t % 12;
    const float* row = &lg[h*144 + i*12];
    float m = row[0];
    for (int j = 1; j < 12; j++) m = fmaxf(m, row[j]);
    float e[12], s = 0.f;
    for (int j = 0; j < 12; j++){ e[j] = __expf(row[j] - m); s += e[j]; }
    float inv = 1.f / s;
    for (int j = 0; j < 12; j++) outB[h*144 + i*12 + j] = e[j] * inv;
  }
}

// ---------------------------------------------------------------------------
// Build fused GAT operator (or plain fW) in MFMA B-frag layout
// [nt][kt][64][8]. grid = nt*KT blocks x 64 threads.
// ---------------------------------------------------------------------------
__global__ void k_prep_op(const float* __restrict__ W, const float* __restrict__ p,
                          int Cin, int Cout, int hdiv, int K, int KT, int N,
                          ushort* __restrict__ dst)
{
  int bI = blockIdx.x;
  int kt = bI % KT, nt = bI / KT;
  int l = threadIdx.x, ln = l & 15, q = l >> 4;
  int n = nt * 16 + ln;
  for (int j = 0; j < 8; j++){
    int k = kt * 32 + q * 8 + j;
    float v = 0.f;
    if (k < K && n < N){
      if (p){
        int jj = k / Cin, kk = k % Cin;
        int i = n / Cout, o = n % Cout;
        v = p[(o / hdiv) * 144 + i * 12 + jj] * W[kk * Cout + o];
      } else {
        v = W[k * Cout + n];
      }
    }
    dst[((long)bI * 64 + l) * 8 + j] = f2b(v);
  }
}

// ---------------------------------------------------------------------------
// Prep LSTM weights -> task-frag layout. Task tau in [0,72): tau<36 -> Whh
// tile (gt=tau/9, ct=tau%9), tau>=36 -> Wih tile. 5 K-frags each (pad 160).
// dst layout per combo: [ntau*5][64][8]. grid dim3(360,4) x 64.
// ---------------------------------------------------------------------------
__global__ void k_prep_lstm(const float* eWih0, const float* eWhh0,
                            const float* eWih1, const float* eWhh1,
                            const float* dWhh0,
                            const float* dWih1, const float* dWhh1,
                            ushort* __restrict__ dstBase)
{
  int combo = blockIdx.y;
  const float* Wh; const float* Wx; long off; int ntau;
  if (combo == 0){ Wh = eWhh0; Wx = eWih0; off = 0;      ntau = 72; }
  else if (combo == 1){ Wh = eWhh1; Wx = eWih1; off = 184320; ntau = 72; }
  else if (combo == 2){ Wh = dWhh0; Wx = dWhh0; off = 368640; ntau = 36; }
  else { Wh = dWhh1; Wx = dWih1; off = 460800; ntau = 72; }
  int bI = blockIdx.x;                 // tau*5 + kt
  int tau = bI / 5, kt = bI % 5;
  if (tau >= ntau) return;
  const float* W = (tau < 36) ? Wh : Wx;
  int tt = (tau < 36) ? tau : tau - 36;
  int gt = tt / 9, ct = tt % 9;
  int l = threadIdx.x, ln = l & 15, q = l >> 4;
  int n = gt * 144 + ct * 16 + ln;
  ushort* d = dstBase + off;
  for (int j = 0; j < 8; j++){
    int k = kt * 32 + q * 8 + j;
    float v = (k < 144) ? W[(long)n * 144 + k] : 0.f;
    d[((long)bI * 64 + l) * 8 + j] = f2b(v);
  }
}

// ---------------------------------------------------------------------------
// GAT layers 0+1 as fused-operator MFMA GEMMs. 512 thr, 128 rows/block.
// ---------------------------------------------------------------------------
__global__ __launch_bounds__(512) void k_gat01(
    const float* __restrict__ x, const ushort* __restrict__ M0f, const float* __restrict__ b0,
    const ushort* __restrict__ M1f, const float* __restrict__ b1,
    ushort* __restrict__ seq)
{
  __shared__ ushort xs[128 * 288];
  __shared__ ushort h1e[128 * 200];
  int t = threadIdx.x;
  long row0 = (long)blockIdx.x * 128;
  int w = t >> 6, l = t & 63, q = l >> 4, ln = l & 15;
  if (t < 384){
    int row = t / 3, seg = t % 3;
    *(uint4*)&xs[row * 288 + 264 + seg * 8] = make_uint4(0u, 0u, 0u, 0u);
  }
  for (int idx = t; idx < 8448; idx += 512){
    int row = idx / 66, c4 = idx % 66;
    float4 v = *(const float4*)&x[(row0 + row) * 264 + c4 * 4];
    ushort4 o; o.x = f2b(v.x); o.y = f2b(v.y); o.z = f2b(v.z); o.w = f2b(v.w);
    *(ushort4*)&xs[row * 288 + c4 * 4] = o;
  }
  int nta[2] = {w, (w < 4) ? 8 + w : -1};
  bfrag8 f0[2][9];
  #pragma unroll
  for (int ii = 0; ii < 2; ii++)
    if (nta[ii] >= 0)
      #pragma unroll
      for (int kt = 0; kt < 9; kt++)
        f0[ii][kt] = *(const bfrag8*)&M0f[((long)(nta[ii] * 9 + kt) * 64 + l) * 8];
  float bias0 = b0[ln];
  __syncthreads();
  for (int rb = 0; rb < 8; rb++){
    bfrag8 af[9];
    #pragma unroll
    for (int kt = 0; kt < 9; kt++)
      af[kt] = *(const bfrag8*)&xs[(rb * 16 + ln) * 288 + kt * 32 + q * 8];
    #pragma unroll
    for (int ii = 0; ii < 2; ii++){
      if (nta[ii] < 0) continue;
      ffrag4 acc = {bias0, bias0, bias0, bias0};
      #pragma unroll
      for (int kt = 0; kt < 9; kt++)
        acc = __builtin_amdgcn_mfma_f32_16x16x32_bf16(af[kt], f0[ii][kt], acc, 0, 0, 0);
      #pragma unroll
      for (int r = 0; r < 4; r++)
        h1e[(rb * 16 + q * 4 + r) * 200 + nta[ii] * 16 + ln] = f2b(elu_(acc[r]));
    }
  }
  int ntb[2] = {w, (w == 0) ? 8 : -1};
  bfrag8 f1[2][6];
  #pragma unroll
  for (int ii = 0; ii < 2; ii++)
    if (ntb[ii] >= 0)
      #pragma unroll
      for (int kt = 0; kt < 6; kt++)
        f1[ii][kt] = *(const bfrag8*)&M1f[((long)(ntb[ii] * 6 + kt) * 64 + l) * 8];
  __syncthreads();
  for (int rb = 0; rb < 8; rb++){
    bfrag8 af[6];
    #pragma unroll
    for (int kt = 0; kt < 6; kt++)
      af[kt] = *(const bfrag8*)&h1e[(rb * 16 + ln) * 200 + kt * 32 + q * 8];
    #pragma unroll
    for (int ii = 0; ii < 2; ii++){
      if (ntb[ii] < 0) continue;
      int n = ntb[ii] * 16 + ln;
      float bias = b1[n % 12];
      ffrag4 acc = {bias, bias, bias, bias};
      #pragma unroll
      for (int kt = 0; kt < 6; kt++)
        acc = __builtin_amdgcn_mfma_f32_16x16x32_bf16(af[kt], f1[ii][kt], acc, 0, 0, 0);
      #pragma unroll
      for (int r = 0; r < 4; r++)
        xs[(rb * 16 + q * 4 + r) * 144 + n] = f2b(elu_(acc[r]));
    }
  }
  __syncthreads();
  for (int i = t; i < 2304; i += 512)
    *(uint4*)&seq[row0 * 144 + (long)i * 8] = *(uint4*)&xs[i * 8];
}

// ---------------------------------------------------------------------------
// LSTM layer scan, 256 blocks x 512 threads (8 waves, 2/SIMD).
// Wave specialization: waves 0-3 (h-waves) hold col-tiles {2w,2w+1} x all 4
// gates in registers -> in-register gate math; plus one gate of tile 8 via a
// small LDS buffer P8. Waves 4-7 (x-waves) compute x-projection for step t+1
// into parity-swapped pad-20 Px (bias baked in), prefetching x(t+2).
// hl (h state) double-buffered by parity. 2 barriers per step.
// ---------------------------------------------------------------------------
template<bool HASX>
__global__ __launch_bounds__(512, 2) void k_scan(
    const ushort* __restrict__ Wf,    // [ntau*5][64][8] frags
    const ushort* __restrict__ seqin, // [24*4096][144] bf16 or null
    const float* __restrict__ bih, const float* __restrict__ bhh,
    const ushort* __restrict__ h0,    // [4096][144] bf16 or null
    ushort* __restrict__ Y,           // [98304][144] bf16 or null
    ushort* __restrict__ hT)          // [4096][144] bf16 or null
{
  __shared__ float Px[2][11520];      // 576 gate-cols x 20 (pad) floats
  __shared__ float P8[1280];          // tile-8 preacts: [gate][16 col][20]
  __shared__ ushort hl[2][2688];      // 16 rows x 168 (pad) bf16
  int t = threadIdx.x, rbk = blockIdx.x;
  int w = t >> 6, l = t & 63, q = l >> 4, ln = l & 15;
  if (t < 336){
    int row = t / 21, ch = t % 21;
    uint4 z = make_uint4(0u, 0u, 0u, 0u);
    if (h0 && ch < 18) z = *(const uint4*)&h0[((long)rbk * 16 + row) * 144 + ch * 8];
    *(uint4*)&hl[0][row * 168 + ch * 8] = z;
    *(uint4*)&hl[1][row * 168 + ch * 8] = make_uint4(0u, 0u, 0u, 0u);
  }
  if (w < 4){
    // ------------------------- h-waves -------------------------
    bfrag8 wh[2][4][5], w8[5];
    #pragma unroll
    for (int ci = 0; ci < 2; ci++)
      #pragma unroll
      for (int gt = 0; gt < 4; gt++)
        #pragma unroll
        for (int kt = 0; kt < 5; kt++)
          wh[ci][gt][kt] = *(const bfrag8*)&Wf[((long)((gt * 9 + 2 * w + ci) * 5 + kt) * 64 + l) * 8];
    #pragma unroll
    for (int kt = 0; kt < 5; kt++)
      w8[kt] = *(const bfrag8*)&Wf[((long)((w * 9 + 8) * 5 + kt) * 64 + l) * 8];
    float cst[2][4] = {};
    float c8 = 0.f;
    __syncthreads();
    for (int ts = 0; ts < 24; ts++){
      int par = ts & 1;
      const ushort* hlr = &hl[par][0];
      ushort* hlw = &hl[par ^ 1][0];
      bfrag8 ah[5];
      #pragma unroll
      for (int kt = 0; kt < 5; kt++)
        ah[kt] = *(const bfrag8*)&hlr[ln * 168 + kt * 32 + q * 8];
      #pragma unroll
      for (int ci = 0; ci < 2; ci++){
        int ct = 2 * w + ci;
        ffrag4 acc[4];
        #pragma unroll
        for (int gt = 0; gt < 4; gt++)
          acc[gt] = *(ffrag4*)&Px[par][(gt * 144 + ct * 16 + ln) * 20 + q * 4];
        #pragma unroll
        for (int gt = 0; gt < 4; gt++)
          #pragma unroll
          for (int kt = 0; kt < 5; kt++)
            acc[gt] = __builtin_amdgcn_mfma_f32_16x16x32_bf16(ah[kt], wh[ci][gt][kt], acc[gt], 0, 0, 0);
        #pragma unroll
        for (int r = 0; r < 4; r++){
          float cn = sigm(acc[1][r]) * cst[ci][r] + sigm(acc[0][r]) * tanh_(acc[2][r]);
          cst[ci][r] = cn;
          ushort hb = f2b(sigm(acc[3][r]) * tanh_(cn));
          hlw[(q * 4 + r) * 168 + ct * 16 + ln] = hb;
          if (Y) Y[(((long)ts * 4096) + rbk * 16 + q * 4 + r) * 144 + ct * 16 + ln] = hb;
        }
      }
      {
        ffrag4 a8 = *(ffrag4*)&Px[par][(w * 144 + 128 + ln) * 20 + q * 4];
        #pragma unroll
        for (int kt = 0; kt < 5; kt++)
          a8 = __builtin_amdgcn_mfma_f32_16x16x32_bf16(ah[kt], w8[kt], a8, 0, 0, 0);
        *(ffrag4*)&P8[(w * 16 + ln) * 20 + q * 4] = a8;
      }
      __syncthreads();
      if (t < 256){
        int row = t >> 4, c8c = t & 15;
        float iv = P8[(0 * 16 + c8c) * 20 + row];
        float fv = P8[(1 * 16 + c8c) * 20 + row];
        float gv = P8[(2 * 16 + c8c) * 20 + row];
        float ov = P8[(3 * 16 + c8c) * 20 + row];
        float cn = sigm(fv) * c8 + sigm(iv) * tanh_(gv);
        c8 = cn;
        ushort hb = f2b(sigm(ov) * tanh_(cn));
        hl[par ^ 1][row * 168 + 128 + c8c] = hb;
        if (Y) Y[(((long)ts * 4096) + rbk * 16 + row) * 144 + 128 + c8c] = hb;
      }
      __syncthreads();
    }
  } else {
    // ------------------------- x-waves -------------------------
    int j = w - 4;
    bfrag8 wx[9][5];
    float biasx[9];
    #pragma unroll
    for (int i = 0; i < 9; i++){
      int n = j * 144 + i * 16 + ln;
      biasx[i] = bih[n] + bhh[n];
      if (HASX)
        #pragma unroll
        for (int kt = 0; kt < 5; kt++)
          wx[i][kt] = *(const bfrag8*)&Wf[((long)((36 + j * 9 + i) * 5 + kt) * 64 + l) * 8];
    }
    bfrag8 axc[5];
    if (HASX){
      const ushort* xr = &seqin[((long)rbk * 16 + ln) * 144];
      #pragma unroll
      for (int kt = 0; kt < 5; kt++)
        axc[kt] = *(const bfrag8*)&xr[kt * 32 + q * 8];
      #pragma unroll
      for (int i = 0; i < 9; i++){
        ffrag4 acc = {biasx[i], biasx[i], biasx[i], biasx[i]};
        #pragma unroll
        for (int kt = 0; kt < 5; kt++)
          acc = __builtin_amdgcn_mfma_f32_16x16x32_bf16(axc[kt], wx[i][kt], acc, 0, 0, 0);
        *(ffrag4*)&Px[0][(j * 144 + i * 16 + ln) * 20 + q * 4] = acc;
      }
      const ushort* xr1 = &seqin[(4096L + (long)rbk * 16 + ln) * 144];
      #pragma unroll
      for (int kt = 0; kt < 5; kt++)
        axc[kt] = *(const bfrag8*)&xr1[kt * 32 + q * 8];
    } else {
      #pragma unroll
      for (int i = 0; i < 9; i++){
        ffrag4 acc = {biasx[i], biasx[i], biasx[i], biasx[i]};
        *(ffrag4*)&Px[0][(j * 144 + i * 16 + ln) * 20 + q * 4] = acc;
        *(ffrag4*)&Px[1][(j * 144 + i * 16 + ln) * 20 + q * 4] = acc;
      }
    }
    __syncthreads();
    for (int ts = 0; ts < 24; ts++){
      if (HASX && ts < 23){
        int par = ts & 1;
        #pragma unroll
        for (int i = 0; i < 9; i++){
          ffrag4 acc = {biasx[i], biasx[i], biasx[i], biasx[i]};
          #pragma unroll
          for (int kt = 0; kt < 5; kt++)
            acc = __builtin_amdgcn_mfma_f32_16x16x32_bf16(axc[kt], wx[i][kt], acc, 0, 0, 0);
          *(ffrag4*)&Px[par ^ 1][(j * 144 + i * 16 + ln) * 20 + q * 4] = acc;
        }
        if (ts < 22){
          const ushort* xr = &seqin[(((long)(ts + 2)) * 4096 + (long)rbk * 16 + ln) * 144];
          #pragma unroll
          for (int kt = 0; kt < 5; kt++)
            axc[kt] = *(const bfrag8*)&xr[kt * 32 + q * 8];
        }
      }
      __syncthreads();
      __syncthreads();
    }
  }
  if (hT && t < 288){
    int row = t / 18, ch = t % 18;
    *(uint4*)&hT[((long)rbk * 16 + row) * 144 + ch * 8] = *(uint4*)&hl[0][row * 168 + ch * 8];
  }
}

// ---------------------------------------------------------------------------
// Tail: GAT3 -> GAT4 -> FC -> leaky -> fused MSE. 512 thr, 128 rows/block.
// ---------------------------------------------------------------------------
__global__ __launch_bounds__(512) void k_tail(
    const ushort* __restrict__ Ya, const ushort* __restrict__ M3f, const float* __restrict__ b3,
    const ushort* __restrict__ M4f, const float* __restrict__ b4,
    const ushort* __restrict__ fWt, const float* __restrict__ fb,
    const float* __restrict__ x, float* __restrict__ out)
{
  __shared__ ushort h3e[128 * 200];
  __shared__ ushort bufB[128 * 288];
  __shared__ float psum[128 * 8];
  ushort* ys = bufB;
  ushort* h4e = bufB;
  int t = threadIdx.x;
  long row0 = (long)blockIdx.x * 128;
  int w = t >> 6, l = t & 63, q = l >> 4, ln = l & 15;
  if (t < 256){
    int row = t / 2, seg = t % 2;
    *(uint4*)&ys[row * 160 + 144 + seg * 8] = make_uint4(0u, 0u, 0u, 0u);
  }
  for (int idx = t; idx < 2304; idx += 512){
    int row = idx / 18, ch = idx % 18;
    *(uint4*)&ys[row * 160 + ch * 8] = *(const uint4*)&Ya[(row0 + row) * 144 + (long)ch * 8];
  }
  int nta[2] = {w, (w < 4) ? 8 + w : -1};
  bfrag8 f3[2][5];
  #pragma unroll
  for (int ii = 0; ii < 2; ii++)
    if (nta[ii] >= 0)
      #pragma unroll
      for (int kt = 0; kt < 5; kt++)
        f3[ii][kt] = *(const bfrag8*)&M3f[((long)(nta[ii] * 5 + kt) * 64 + l) * 8];
  float bias3 = b3[ln];
  __syncthreads();
  for (int rb = 0; rb < 8; rb++){
    bfrag8 af[5];
    #pragma unroll
    for (int kt = 0; kt < 5; kt++)
      af[kt] = *(const bfrag8*)&ys[(rb * 16 + ln) * 160 + kt * 32 + q * 8];
    #pragma unroll
    for (int ii = 0; ii < 2; ii++){
      if (nta[ii] < 0) continue;
      ffrag4 acc = {bias3, bias3, bias3, bias3};
      #pragma unroll
      for (int kt = 0; kt < 5; kt++)
        acc = __builtin_amdgcn_mfma_f32_16x16x32_bf16(af[kt], f3[ii][kt], acc, 0, 0, 0);
      #pragma unroll
      for (int r = 0; r < 4; r++)
        h3e[(rb * 16 + q * 4 + r) * 200 + nta[ii] * 16 + ln] = f2b(elu_(acc[r]));
    }
  }
  int ntb[3] = {2 * w, 2 * w + 1, (w < 2) ? 16 + w : -1};
  bfrag8 f4[3][6];
  #pragma unroll
  for (int ii = 0; ii < 3; ii++)
    if (ntb[ii] >= 0)
      #pragma unroll
      for (int kt = 0; kt < 6; kt++)
        f4[ii][kt] = *(const bfrag8*)&M4f[((long)(ntb[ii] * 6 + kt) * 64 + l) * 8];
  __syncthreads();
  for (int rb = 0; rb < 8; rb++){
    bfrag8 af[6];
    #pragma unroll
    for (int kt = 0; kt < 6; kt++)
      af[kt] = *(const bfrag8*)&h3e[(rb * 16 + ln) * 200 + kt * 32 + q * 8];
    #pragma unroll
    for (int ii = 0; ii < 3; ii++){
      if (ntb[ii] < 0) continue;
      int n = ntb[ii] * 16 + ln;
      float bias = b4[n % 24];
      ffrag4 acc = {bias, bias, bias, bias};
      #pragma unroll
      for (int kt = 0; kt < 6; kt++)
        acc = __builtin_amdgcn_mfma_f32_16x16x32_bf16(af[kt], f4[ii][kt], acc, 0, 0, 0);
      #pragma unroll
      for (int r = 0; r < 4; r++)
        h4e[(rb * 16 + q * 4 + r) * 288 + n] = f2b(elu_(acc[r]));
    }
  }
  int ntc[3] = {2 * w, 2 * w + 1, (w == 0) ? 16 : -1};
  bfrag8 f5[3][9];
  float bias5[3] = {0.f, 0.f, 0.f};
  #pragma unroll
  for (int ii = 0; ii < 3; ii++)
    if (ntc[ii] >= 0){
      #pragma unroll
      for (int kt = 0; kt < 9; kt++)
        f5[ii][kt] = *(const bfrag8*)&fWt[((long)(ntc[ii] * 9 + kt) * 64 + l) * 8];
      int n = ntc[ii] * 16 + ln;
      bias5[ii] = (n < 264) ? fb[n] : 0.f;
    }
  __syncthreads();
  for (int rb = 0; rb < 8; rb++){
    bfrag8 af[9];
    #pragma unroll
    for (int kt = 0; kt < 9; kt++)
      af[kt] = *(const bfrag8*)&h4e[(rb * 16 + ln) * 288 + kt * 32 + q * 8];
    float s4[4] = {0.f, 0.f, 0.f, 0.f};
    #pragma unroll
    for (int ii = 0; ii < 3; ii++){
      if (ntc[ii] < 0) continue;
      ffrag4 acc = {bias5[ii], bias5[ii], bias5[ii], bias5[ii]};
      #pragma unroll
      for (int kt = 0; kt < 9; kt++)
        acc = __builtin_amdgcn_mfma_f32_16x16x32_bf16(af[kt], f5[ii][kt], acc, 0, 0, 0);
      int n = ntc[ii] * 16 + ln;
      if (n < 264){
        #pragma unroll
        for (int r = 0; r < 4; r++){
          float v = acc[r];
          v = v > 0.f ? v : 0.01f * v;
          long row = row0 + rb * 16 + q * 4 + r;
          float d = x[row * 264 + n] - v;
          s4[r] += d * d;
        }
      }
    }
    #pragma unroll
    for (int off = 1; off < 16; off <<= 1){
      #pragma unroll
      for (int r = 0; r < 4; r++) s4[r] += __shfl_xor(s4[r], off, 16);
    }
    if (ln == 0){
      #pragma unroll
      for (int r = 0; r < 4; r++) psum[(rb * 16 + q * 4 + r) * 8 + w] = s4[r];
    }
  }
  __syncthreads();
  if (t < 128){
    float s = 0.f;
    for (int k = 0; k < 8; k++) s += psum[t * 8 + k];
    out[row0 + t] = s * (1.0f / 264.0f);
  }
}

// ---------------------------------------------------------------------------
extern "C" void kernel_launch(void* const* d_in, const int* in_sizes, int n_in,
                              void* d_out, int out_size, void* d_ws, size_t ws_size,
                              hipStream_t stream)
{
  const float* x     = (const float*)d_in[0];
  const float* gW0   = (const float*)d_in[1];
  const float* gb0   = (const float*)d_in[2];
  const float* ga0   = (const float*)d_in[3];
  const float* gW1   = (const float*)d_in[4];
  const float* gb1   = (const float*)d_in[5];
  const float* ga1   = (const float*)d_in[6];
  const float* eWih0 = (const float*)d_in[7];
  const float* eWhh0 = (const float*)d_in[8];
  const float* ebih0 = (const float*)d_in[9];
  const float* ebhh0 = (const float*)d_in[10];
  const float* eWih1 = (const float*)d_in[11];
  const float* eWhh1 = (const float*)d_in[12];
  const float* ebih1 = (const float*)d_in[13];
  const float* ebhh1 = (const float*)d_in[14];
  const float* dWhh0 = (const float*)d_in[16];
  const float* dbih0 = (const float*)d_in[17];
  const float* dbhh0 = (const float*)d_in[18];
  const float* dWih1 = (const float*)d_in[19];
  const float* dWhh1 = (const float*)d_in[20];
  const float* dbih1 = (const float*)d_in[21];
  const float* dbhh1 = (const float*)d_in[22];
  const float* gW3   = (const float*)d_in[23];
  const float* gb3   = (const float*)d_in[24];
  const float* ga3   = (const float*)d_in[25];
  const float* gW4   = (const float*)d_in[26];
  const float* gb4   = (const float*)d_in[27];
  const float* ga4   = (const float*)d_in[28];
  const float* fW    = (const float*)d_in[29];
  const float* fb    = (const float*)d_in[30];

  char* ws = (char*)d_ws;
  float*  probs0 = (float*)(ws + 0);
  float*  probs1 = (float*)(ws + 2304);
  float*  probs3 = (float*)(ws + 4608);
  float*  probs4 = (float*)(ws + 6912);
  ushort* M0f    = (ushort*)(ws + 9216);       // 110592 B
  ushort* M1f    = (ushort*)(ws + 119808);     // 55296 B
  ushort* M3f    = (ushort*)(ws + 175104);     // 61440 B
  ushort* M4f    = (ushort*)(ws + 236544);     // 110592 B
  ushort* fWt    = (ushort*)(ws + 347136);     // 156672 B
  ushort* lstmF  = (ushort*)(ws + 503808);     // 1290240 B
  ushort* seq    = (ushort*)(ws + 1794048);    // 28311552 B
  ushort* Ya     = (ushort*)(ws + 30105600);   // 28311552 B
  ushort* Yb     = (ushort*)(ws + 58417152);   // 28311552 B
  ushort* hT0    = (ushort*)(ws + 86728704);   // 1179648 B
  ushort* hT1    = (ushort*)(ws + 87908352);   // 1179648 B
  float* out = (float*)d_out;

  k_prep_lstm<<<dim3(360, 4), 64, 0, stream>>>(eWih0, eWhh0, eWih1, eWhh1,
                                               dWhh0, dWih1, dWhh1, lstmF);
  k_prep_op<<<153, 64, 0, stream>>>(fW, nullptr, 0, 264, 1, 288, 9, 264, fWt);
  k_probs<<<1, 576, 0, stream>>>(x, nullptr, 22,
                                 gW0, gb0, ga0, 16, 4,
                                 gW1, gb1, ga1, 12, 3,
                                 probs0, probs1);
  k_prep_op<<<108, 64, 0, stream>>>(gW0, probs0, 22, 16, 4, 264, 9, 192, M0f);
  k_prep_op<<<54, 64, 0, stream>>>(gW1, probs1, 16, 12, 3, 192, 6, 144, M1f);
  k_gat01<<<768, 512, 0, stream>>>(x, M0f, gb0, M1f, gb1, seq);

  // encoder L0
  k_scan<true><<<256, 512, 0, stream>>>(lstmF + 0L,      seq, ebih0, ebhh0, nullptr, Ya, hT0);
  // encoder L1 (only final h needed)
  k_scan<true><<<256, 512, 0, stream>>>(lstmF + 184320L, Ya, ebih1, ebhh1, nullptr, nullptr, hT1);
  // decoder L0 (zero input)
  k_scan<false><<<256, 512, 0, stream>>>(lstmF + 368640L, nullptr, dbih0, dbhh0, hT0, Yb, nullptr);
  // decoder L1
  k_scan<true><<<256, 512, 0, stream>>>(lstmF + 460800L, Yb, dbih1, dbhh1, hT1, Ya, nullptr);

  k_probs<<<1, 576, 0, stream>>>(nullptr, Ya, 12,
                                 gW3, gb3, ga3, 16, 4,
                                 gW4, gb4, ga4, 24, 6,
                                 probs3, probs4);
  k_prep_op<<<60, 64, 0, stream>>>(gW3, probs3, 12, 16, 4, 144, 5, 192, M3f);
  k_prep_op<<<108, 64, 0, stream>>>(gW4, probs4, 16, 24, 6, 192, 6, 288, M4f);
  k_tail<<<768, 512, 0, stream>>>(Ya, M3f, gb3, M4f, gb4, fWt, fb, x, out);
}